// Round 6
// baseline (72.179 us; speedup 1.0000x reference)
//
#include <hip/hip_runtime.h>
#include <stdint.h>

#define BATCH 16
#define NPIX 200704   // 448*448
#define HB 64
#define EPS 1e-6f
#define WINW 16384    // 64 KB LDS window (words)

// K(j,g) = 1 / (1 + ((c_j - b_g)/sigma)^2), c_j=(j+0.5)/W, b_g=g/63, 1/sigma=50
__device__ __forceinline__ float kval(int j, int g, float invW) {
  float d = (((float)j + 0.5f) * invW - (float)g * (1.0f / 63.0f)) * 50.0f;
  return 1.0f / (1.0f + d * d);
}

// ---------------- pass 1: chroma -> fine-grid id per pixel (XCD-pinned by batch) ----------------
__global__ __launch_bounds__(256) void make_ids(const float* __restrict__ x,
                                                unsigned int* __restrict__ ids,
                                                int W, int nb) {
  int bid = blockIdx.x;
  int xcd = bid & 7;
  int t = bid >> 3;
  int c = t % nb;
  int b = xcd + 8 * (t / nb);
  int q = c * 256 + threadIdx.x;                    // uint4 index within batch
  const float4* R  = (const float4*)(x + (size_t)b * 3 * NPIX);
  const float4* G  = R + (NPIX / 4);
  const float4* Bl = G + (NPIX / 4);
  float4 rv = R[q], gv = G[q], bv = Bl[q];
  float fW = (float)W;
  float rr[4] = {rv.x, rv.y, rv.z, rv.w};
  float gg[4] = {gv.x, gv.y, gv.z, gv.w};
  float bb[4] = {bv.x, bv.y, bv.z, bv.w};
  unsigned int o[4];
#pragma unroll
  for (int t2 = 0; t2 < 4; t2++) {
    float r  = fminf(fmaxf(rr[t2], 0.0f), 1.0f);
    float g  = fminf(fmaxf(gg[t2], 0.0f), 1.0f);
    float bl = fminf(fmaxf(bb[t2], 0.0f), 1.0f);
    float inv = 1.0f / (r + g + bl + EPS);
    int i = min((int)(r * inv * fW), W - 1);
    int j = min((int)(g * inv * fW), W - 1);
    o[t2] = (unsigned int)(i * W + j);
  }
  ((uint4*)(ids + (size_t)b * NPIX))[q] = make_uint4(o[0], o[1], o[2], o[3]);
}

// ---------------- pass 2: per-(batch,window) LDS histogram, float flush ----------------
__global__ __launch_bounds__(1024) void hist_window(const unsigned int* __restrict__ ids,
                                                    float* __restrict__ Hf,
                                                    int W, int nwin) {
  __shared__ unsigned int sh[WINW];
  int bid = blockIdx.x;
  int xcd = bid & 7;
  int t0 = bid >> 3;
  unsigned int w = (unsigned int)(t0 % nwin);
  int b = xcd + 8 * (t0 / nwin);
  int tid = threadIdx.x;
  for (int t = tid; t < WINW; t += 1024) sh[t] = 0u;
  __syncthreads();
  const uint4* idv = (const uint4*)(ids + (size_t)b * NPIX);
  for (int t = tid; t < NPIX / 4; t += 1024) {
    uint4 v = idv[t];
    if ((v.x >> 14) == w) atomicAdd(&sh[v.x & 16383u], 1u);
    if ((v.y >> 14) == w) atomicAdd(&sh[v.y & 16383u], 1u);
    if ((v.z >> 14) == w) atomicAdd(&sh[v.z & 16383u], 1u);
    if ((v.w >> 14) == w) atomicAdd(&sh[v.w & 16383u], 1u);
  }
  __syncthreads();
  float4* dst = (float4*)(Hf + (size_t)b * W * W + (size_t)w * WINW);
  for (int t = tid; t < WINW / 4; t += 1024) {
    uint4 v = ((const uint4*)sh)[t];
    dst[t] = make_float4((float)v.x, (float)v.y, (float)v.z, (float)v.w);
  }
}

// ---------------- fused stage B+C:
// M_tile[i][g] = sum_{j in q-slice} H[itile*64+i][j] * K[j][g]   (registers)
// P[b][itile*Q+q][r][g] = sum_{i=0..63} K[itile*64+i][r] * M_tile[i][g]
__global__ __launch_bounds__(256) void stageBC(const float* __restrict__ Hf,
                                               float* __restrict__ P, int W, int Q) {
  int ntile = W >> 6;
  int bid = blockIdx.x;
  int xcd = bid & 7;
  int t0 = bid >> 3;
  int q = t0 % Q; t0 /= Q;
  int itile = t0 % ntile;
  int b = xcd + 8 * (t0 / ntile);
  __shared__ float sH[64][68];    // H tile (padded); reused as K_C in epilogue
  __shared__ float sK[64][64];    // K tile; reused as M tile in epilogue
  int tid = threadIdx.x;
  int gq4 = (tid & 15) * 4;
  int iq4 = (tid >> 4) * 4;       // i-quad in main loop; r-quad in epilogue
  float invW = 1.0f / (float)W;
  float acc[4][4];
#pragma unroll
  for (int a = 0; a < 4; a++)
#pragma unroll
    for (int c = 0; c < 4; c++) acc[a][c] = 0.0f;

  int jspan = W / Q;            // 128
  int jbase = q * jspan;
  int nch = jspan >> 6;         // 2
  const float* Hbase = Hf + ((size_t)b * W + (size_t)itile * 64) * W;

  for (int ch = 0; ch < nch; ch++) {
    int j0 = jbase + ch * 64;
#pragma unroll
    for (int rep = 0; rep < 4; rep++) {           // 1024 float4: H tile 64x64
      int idx = rep * 256 + tid;
      int ii = idx >> 4, jj4 = (idx & 15) * 4;
      float4 v = *(const float4*)&Hbase[(size_t)ii * W + (j0 + jj4)];
      *(float4*)&sH[ii][jj4] = v;
    }
#pragma unroll
    for (int rep = 0; rep < 4; rep++) {           // K tile 64x64 computed in-place
      int idx = rep * 256 + tid;
      int jr = idx >> 4, g4 = (idx & 15) * 4;
      int jj = j0 + jr;
      sK[jr][g4 + 0] = kval(jj, g4 + 0, invW);
      sK[jr][g4 + 1] = kval(jj, g4 + 1, invW);
      sK[jr][g4 + 2] = kval(jj, g4 + 2, invW);
      sK[jr][g4 + 3] = kval(jj, g4 + 3, invW);
    }
    __syncthreads();
#pragma unroll 4
    for (int tt = 0; tt < 16; tt++) {             // 4 jp per step, all b128
      float hh[4][4], kk[4][4];
#pragma unroll
      for (int di = 0; di < 4; di++) {
        float4 v = *(const float4*)&sH[iq4 + di][tt * 4];
        hh[di][0] = v.x; hh[di][1] = v.y; hh[di][2] = v.z; hh[di][3] = v.w;
      }
#pragma unroll
      for (int p = 0; p < 4; p++) {
        float4 v = *(const float4*)&sK[tt * 4 + p][gq4];
        kk[p][0] = v.x; kk[p][1] = v.y; kk[p][2] = v.z; kk[p][3] = v.w;
      }
#pragma unroll
      for (int p = 0; p < 4; p++)
#pragma unroll
        for (int di = 0; di < 4; di++)
#pragma unroll
          for (int dg = 0; dg < 4; dg++)
            acc[di][dg] = fmaf(hh[di][p], kk[p][dg], acc[di][dg]);
    }
    __syncthreads();
  }

  // ---- epilogue: P_slice = K_C^T * M_tile, all on-chip ----
  // M tile -> sK (rows=i, cols=g); K_C -> sH (rows=i, cols=r)
#pragma unroll
  for (int di = 0; di < 4; di++) {
    float4 v = make_float4(acc[di][0], acc[di][1], acc[di][2], acc[di][3]);
    *(float4*)&sK[iq4 + di][gq4] = v;
  }
  int i0 = itile * 64;
#pragma unroll
  for (int rep = 0; rep < 4; rep++) {
    int idx = rep * 256 + tid;
    int ii = idx >> 4, r4b = (idx & 15) * 4;
    sH[ii][r4b + 0] = kval(i0 + ii, r4b + 0, invW);
    sH[ii][r4b + 1] = kval(i0 + ii, r4b + 1, invW);
    sH[ii][r4b + 2] = kval(i0 + ii, r4b + 2, invW);
    sH[ii][r4b + 3] = kval(i0 + ii, r4b + 3, invW);
  }
  __syncthreads();
  float acc2[4][4];
#pragma unroll
  for (int a = 0; a < 4; a++)
#pragma unroll
    for (int c = 0; c < 4; c++) acc2[a][c] = 0.0f;
#pragma unroll 8
  for (int ip = 0; ip < 64; ip++) {
    float4 kc = *(const float4*)&sH[ip][iq4];   // broadcast within 16-lane groups
    float4 mm = *(const float4*)&sK[ip][gq4];
    float kk2[4] = {kc.x, kc.y, kc.z, kc.w};
    float mv[4] = {mm.x, mm.y, mm.z, mm.w};
#pragma unroll
    for (int dr = 0; dr < 4; dr++)
#pragma unroll
      for (int dg = 0; dg < 4; dg++)
        acc2[dr][dg] = fmaf(kk2[dr], mv[dg], acc2[dr][dg]);
  }
  int slice = itile * Q + q;
  float* Pb = P + (((size_t)b * (ntile * Q)) + slice) * 4096;
#pragma unroll
  for (int dr = 0; dr < 4; dr++) {
    float4 v = make_float4(acc2[dr][0], acc2[dr][1], acc2[dr][2], acc2[dr][3]);
    *(float4*)&Pb[(size_t)(iq4 + dr) * 64 + gq4] = v;
  }
}

// ---------------- fused stage D: reduce slices, normalize, store ----------------
__global__ __launch_bounds__(1024) void stageDall(const float* __restrict__ P,
                                                  float* __restrict__ out, int nslice) {
  int b = blockIdx.x;                 // 16 blocks; b%8 matches producer XCD pinning
  int tid = threadIdx.x;
  const float* Pb = P + (size_t)b * nslice * 4096;
  float un[4];
  float psum = 0.0f;
#pragma unroll
  for (int k = 0; k < 4; k++) {
    int rg = k * 1024 + tid;
    float s = 0.0f;
    for (int c = 0; c < nslice; c++) s += Pb[(size_t)c * 4096 + rg];
    un[k] = s;
    psum += s;
  }
  __shared__ float red[1024];
  red[tid] = psum;
  __syncthreads();
  for (int st = 512; st > 0; st >>= 1) {
    if (tid < st) red[tid] += red[tid + st];
    __syncthreads();
  }
  float inv = 1.0f / (red[0] + EPS);
#pragma unroll
  for (int k = 0; k < 4; k++) {
    int rg = k * 1024 + tid;
    out[(size_t)b * 4096 + rg] = un[k] * inv;
  }
}

extern "C" void kernel_launch(void* const* d_in, const int* in_sizes, int n_in,
                              void* d_out, int out_size, void* d_ws, size_t ws_size,
                              hipStream_t stream) {
  const float* x = (const float*)d_in[0];
  float* out = (float*)d_out;

  // W: multiple of 128 with W^2 a multiple of 16384. 384 preferred.
  int W = 384;
  for (;;) {
    int Qtry = W >> 7; if (Qtry < 1) Qtry = 1;
    int nslice_try = (W >> 6) * Qtry;
    size_t need = (size_t)BATCH * W * W * 4             // H (float)
                + (size_t)BATCH * NPIX * 4              // pixel ids
                + (size_t)BATCH * nslice_try * 4096 * 4; // P partial hists
    if (need <= ws_size || W == 128) break;
    W = (W == 384) ? 256 : 128;
  }
  int Q = W >> 7; if (Q < 1) Q = 1;
  int ntile = W >> 6;
  int nslice = ntile * Q;
  int nwin = (W * W) / WINW; if (nwin < 1) nwin = 1;
  int nb = NPIX / 4 / 256;   // 196 pixel-chunks per batch in make_ids

  char* p = (char*)d_ws;
  float* Hf = (float*)p;                p += (size_t)BATCH * W * W * 4;
  unsigned int* ids = (unsigned int*)p; p += (size_t)BATCH * NPIX * 4;
  float* P = (float*)p;

  make_ids<<<BATCH * nb, 256, 0, stream>>>(x, ids, W, nb);
  hist_window<<<BATCH * nwin, 1024, 0, stream>>>(ids, Hf, W, nwin);
  stageBC<<<BATCH * ntile * Q, 256, 0, stream>>>(Hf, P, W, Q);
  stageDall<<<BATCH, 1024, 0, stream>>>(P, out, nslice);
}